// Round 4
// baseline (6669.569 us; speedup 1.0000x reference)
//
#include <hip/hip_runtime.h>
#include <math.h>

#define NN 2048
#define BB 32
#define LL 12
#define HHH 12
#define UU 64
#define STR 68                 // padded row width: [h 64 | x 2 | pad 2]
#define SLAB (BB*STR)          // 2176 u32 per node
#define SEGP (SLAB/4)          // 544
#define MR (NN*BB)             // 65536
#define CSR_CAP 262144
#define PACK_HALF 28672        // 7ks*4nf*2prec*64lane*8j halfwords per 64-col half

typedef short bfrag __attribute__((ext_vector_type(8)));
typedef float ffrag __attribute__((ext_vector_type(4)));

// ---- packed split-bf16: u32 = (bf16(x)<<16) | bf16(x - hi); value = hi_f + lo_f ----
__device__ __forceinline__ unsigned packsf(float x) {
  unsigned u = __float_as_uint(x);
  unsigned hb = (u + 0x7FFFu + ((u >> 16) & 1u)) & 0xFFFF0000u;
  float rem = x - __uint_as_float(hb);
  unsigned lb = __float_as_uint(rem) >> 16;
  return hb | lb;
}
__device__ __forceinline__ float recsf(unsigned u) {
  return __uint_as_float(u & 0xFFFF0000u) + __uint_as_float(u << 16);
}
__device__ __forceinline__ float sigm(float x) { return 1.0f / (1.0f + __expf(-x)); }
__device__ __forceinline__ float tanhfast(float x) {
  float e = __expf(2.0f * x);
  return 1.0f - 2.0f / (e + 1.0f);
}

// ---------------- CSR build (deterministic) ----------------
__global__ __launch_bounds__(256) void k_row_count(const float* __restrict__ S, int* __restrict__ cnt) {
  int m = blockIdx.x;
  const float* row = S + (size_t)m * NN;
  int c = 0;
  for (int i = threadIdx.x; i < NN; i += 256) c += (row[i] != 0.0f);
  __shared__ int sm[4];
  for (int off = 32; off; off >>= 1) c += __shfl_down(c, off, 64);
  if ((threadIdx.x & 63) == 0) sm[threadIdx.x >> 6] = c;
  __syncthreads();
  if (threadIdx.x == 0) cnt[m] = sm[0] + sm[1] + sm[2] + sm[3];
}

__global__ __launch_bounds__(256) void k_scan(const int* __restrict__ cnt, int* __restrict__ rp) {
  __shared__ int tot[256];
  int t = threadIdx.x;
  int base = t * 8;
  int v[8]; int s = 0;
  #pragma unroll
  for (int k = 0; k < 8; ++k) { v[k] = cnt[base + k]; s += v[k]; }
  tot[t] = s;
  __syncthreads();
  for (int off = 1; off < 256; off <<= 1) {
    int add = (t >= off) ? tot[t - off] : 0;
    __syncthreads();
    tot[t] += add;
    __syncthreads();
  }
  int run = (t == 0) ? 0 : tot[t - 1];
  #pragma unroll
  for (int k = 0; k < 8; ++k) { rp[base + k] = run; run += v[k]; }
  if (t == 255) rp[NN] = run;
}

__global__ __launch_bounds__(256) void k_fill(const float* __restrict__ S, const int* __restrict__ rp,
                                              int* __restrict__ cols, float* __restrict__ vals) {
  int m = blockIdx.x;
  const float* row = S + (size_t)m * NN;
  __shared__ int wsum[4];
  __shared__ int chunkbase;
  if (threadIdx.x == 0) chunkbase = rp[m];
  __syncthreads();
  int lane = threadIdx.x & 63, w = threadIdx.x >> 6;
  for (int ch = 0; ch < NN / 256; ++ch) {
    int i = ch * 256 + threadIdx.x;
    float val = row[i];
    bool p = (val != 0.0f);
    unsigned long long mask = __ballot(p);
    int rank = __popcll(mask & ((1ull << lane) - 1ull));
    if (lane == 0) wsum[w] = __popcll(mask);
    __syncthreads();
    int off = 0;
    for (int q = 0; q < w; ++q) off += wsum[q];
    if (p) { int k = chunkbase + off + rank; cols[k] = i; vals[k] = val; }
    __syncthreads();
    if (threadIdx.x == 0) chunkbase += wsum[0] + wsum[1] + wsum[2] + wsum[3];
    __syncthreads();
  }
}

// ---------------- weight pack: fragment-linear bf16 hi/lo ----------------
__global__ __launch_bounds__(256) void k_pack(const float* __restrict__ Wsrc, unsigned short* __restrict__ dst,
                                              int CIN_, int NO) {
  int idx = blockIdx.x * 256 + threadIdx.x;
  int nh_count = NO >> 6;
  int tot = nh_count * 7 * 4 * 64 * 8;
  if (idx >= tot) return;
  int j = idx & 7;
  int r1 = idx >> 3;  int lane = r1 & 63;
  int r2 = r1 >> 6;   int nf = r2 & 3;
  int r3 = r2 >> 2;   int ks = r3 % 7; int nh = r3 / 7;
  int grp = lane >> 4, l15 = lane & 15;
  int col = nh*64 + nf*16 + l15;
  float wv = 0.0f;
  if (ks < 6) {
    int kb = ks >> 1;
    int c = CIN_ + (ks & 1)*32 + grp*8 + j;
    wv = Wsrc[((size_t)c*3 + kb)*NO + col];
  } else {
    int q = grp*8 + j;
    if (q < 3*CIN_) { int kb = q / CIN_, c = q % CIN_; wv = Wsrc[((size_t)c*3 + kb)*NO + col]; }
  }
  unsigned pw = packsf(wv);
  size_t basehi = ((size_t)nh*PACK_HALF) + ((((size_t)ks*4 + nf)*2 + 0)*64 + lane)*8 + j;
  size_t baselo = ((size_t)nh*PACK_HALF) + ((((size_t)ks*4 + nf)*2 + 1)*64 + lane)*8 + j;
  dst[basehi] = (unsigned short)(pw >> 16);
  dst[baselo] = (unsigned short)(pw & 0xFFFFu);
}

__global__ __launch_bounds__(256) void k_packt(const float* __restrict__ src, unsigned* __restrict__ dst, int n) {
  int i = blockIdx.x * 256 + threadIdx.x;
  if (i < n) dst[i] = packsf(src[i]);
}

// ---------------- hop-1: T1 = S . X   (packed in, packed out) ----------------
// SRC: 0 = z-slab, 1 = enc cat [h|hist], 2 = dec cat [h|xio]
template<int SRC>
__global__ __launch_bounds__(256) void k_hop(
    const int* __restrict__ rp, const int* __restrict__ cols, const float* __restrict__ vals,
    const unsigned* __restrict__ src, const unsigned* __restrict__ xP,
    const unsigned* __restrict__ hP, unsigned* __restrict__ Y, int t) {
  __shared__ int   scol[64];
  __shared__ float sval[64];
  int orig = blockIdx.x;
  int swz = (orig & 7) * 1024 + (orig >> 3);     // bijective XCD swizzle
  int seg = swz >> 11;
  int node = swz & 2047;
  int j0 = rp[node], j1 = rp[node + 1];
  int tid = threadIdx.x;
  int w0 = seg * SEGP + tid, w1 = w0 + 256, w2 = w0 + 512;
  bool a2 = tid < (SEGP - 512);
  float acc0 = 0.f, acc1 = 0.f, acc2 = 0.f;
  int b0 = 0, c0 = 0, b1 = 0, c1 = 0, b2 = 0, c2 = 0;
  if constexpr (SRC != 0) {
    b0 = w0 / STR; c0 = w0 - b0 * STR;
    b1 = w1 / STR; c1 = w1 - b1 * STR;
    b2 = w2 / STR; c2 = w2 - b2 * STR;
  }
  auto XV = [&](int n, int wq, int b, int c) -> float {
    if constexpr (SRC == 0) {
      return recsf(src[(size_t)n * SLAB + wq]);
    } else {
      if (c < 64) return recsf(hP[((size_t)n * BB + b) * UU + c]);
      if constexpr (SRC == 1) {
        if (c < 66) return recsf(xP[(((size_t)(b * LL + t)) * NN + n) * 2 + (c - 64)]);
        return 0.f;
      } else {
        if (c == 64) return recsf(xP[(size_t)n * BB + b]);
        return 0.f;
      }
    }
  };
  for (int base = j0; base < j1; base += 64) {
    int cnt = min(64, j1 - base);
    if (tid < cnt) { scol[tid] = cols[base + tid]; sval[tid] = vals[base + tid]; }
    __syncthreads();
    int jj = 0;
    for (; jj + 4 <= cnt; jj += 4) {
      int   n0 = scol[jj], n1 = scol[jj+1], n2 = scol[jj+2], n3 = scol[jj+3];
      float s0 = sval[jj], s1 = sval[jj+1], s2 = sval[jj+2], s3 = sval[jj+3];
      float v00 = XV(n0, w0, b0, c0), v10 = XV(n1, w0, b0, c0);
      float v20 = XV(n2, w0, b0, c0), v30 = XV(n3, w0, b0, c0);
      float v01 = XV(n0, w1, b1, c1), v11 = XV(n1, w1, b1, c1);
      float v21 = XV(n2, w1, b1, c1), v31 = XV(n3, w1, b1, c1);
      float v02 = 0.f, v12 = 0.f, v22 = 0.f, v32 = 0.f;
      if (a2) {
        v02 = XV(n0, w2, b2, c2); v12 = XV(n1, w2, b2, c2);
        v22 = XV(n2, w2, b2, c2); v32 = XV(n3, w2, b2, c2);
      }
      acc0 = fmaf(s0, v00, acc0); acc0 = fmaf(s1, v10, acc0);
      acc0 = fmaf(s2, v20, acc0); acc0 = fmaf(s3, v30, acc0);
      acc1 = fmaf(s0, v01, acc1); acc1 = fmaf(s1, v11, acc1);
      acc1 = fmaf(s2, v21, acc1); acc1 = fmaf(s3, v31, acc1);
      acc2 = fmaf(s0, v02, acc2); acc2 = fmaf(s1, v12, acc2);
      acc2 = fmaf(s2, v22, acc2); acc2 = fmaf(s3, v32, acc2);
    }
    for (; jj < cnt; ++jj) {
      int n = scol[jj]; float s = sval[jj];
      acc0 = fmaf(s, XV(n, w0, b0, c0), acc0);
      acc1 = fmaf(s, XV(n, w1, b1, c1), acc1);
      if (a2) acc2 = fmaf(s, XV(n, w2, b2, c2), acc2);
    }
    __syncthreads();
  }
  unsigned* yr = Y + (size_t)node * SLAB;
  yr[w0] = packsf(acc0);
  yr[w1] = packsf(acc1);
  if (a2) yr[w2] = packsf(acc2);
}

// ================= fused gate: T2 local + GEMM(224x128) + sigmoid + z/Ug =================
template<int CATM>   // 1 enc, 2 dec
__global__ __launch_bounds__(256) void k_gate(
    const unsigned* __restrict__ hP, const unsigned* __restrict__ xP,
    const unsigned* __restrict__ T1P,
    const unsigned short* __restrict__ Bpack, const float* __restrict__ bg,
    const int* __restrict__ rp, const int* __restrict__ cols, const float* __restrict__ vals,
    unsigned* __restrict__ zP, float* __restrict__ Ug, int t) {
  __shared__ __align__(16) unsigned short T2hi[4*32*72];
  __shared__ __align__(16) unsigned short T2lo[4*32*72];
  int tid = threadIdx.x;
  int nd0 = blockIdx.x * 4;
  // ---- phase 1: T2 = 2 S T1 - cat (local, packed in LDS split planes) ----
  bool k8 = tid < (SLAB - 2048);
  for (int q = 0; q < 4; ++q) {
    int node = nd0 + q;
    int j0 = rp[node], j1 = rp[node + 1];
    float fa[9];
    #pragma unroll
    for (int k = 0; k < 9; ++k) fa[k] = 0.f;
    int j = j0;
    for (; j + 2 <= j1; j += 2) {
      int n0 = cols[j], n1 = cols[j + 1];
      float s0 = vals[j], s1 = vals[j + 1];
      const unsigned* p0 = T1P + (size_t)n0 * SLAB + tid;
      const unsigned* p1 = T1P + (size_t)n1 * SLAB + tid;
      unsigned u0[9], u1[9];
      #pragma unroll
      for (int k = 0; k < 8; ++k) { u0[k] = p0[k*256]; u1[k] = p1[k*256]; }
      u0[8] = k8 ? p0[2048] : 0u;
      u1[8] = k8 ? p1[2048] : 0u;
      #pragma unroll
      for (int k = 0; k < 9; ++k) {
        fa[k] = fmaf(s0, recsf(u0[k]), fa[k]);
        fa[k] = fmaf(s1, recsf(u1[k]), fa[k]);
      }
    }
    if (j < j1) {
      int n0 = cols[j]; float s0 = vals[j];
      const unsigned* p0 = T1P + (size_t)n0 * SLAB + tid;
      unsigned u0[9];
      #pragma unroll
      for (int k = 0; k < 8; ++k) u0[k] = p0[k*256];
      u0[8] = k8 ? p0[2048] : 0u;
      #pragma unroll
      for (int k = 0; k < 9; ++k) fa[k] = fmaf(s0, recsf(u0[k]), fa[k]);
    }
    #pragma unroll
    for (int k = 0; k < 9; ++k) {
      int idx = tid + k*256;
      if (idx < SLAB) {
        int b = idx / STR, c = idx - b*STR;
        int grow = node*BB + b;
        float x0;
        if (c < 64) x0 = recsf(hP[(size_t)grow*UU + c]);
        else if (CATM == 1) x0 = (c < 66) ? recsf(xP[(((size_t)(b*LL + t))*NN + node)*2 + (c - 64)]) : 0.f;
        else x0 = (c == 64) ? recsf(xP[grow]) : 0.f;
        unsigned py = packsf(2.f*fa[k] - x0);
        int sa = (q*32 + b)*72 + c;
        T2hi[sa] = (unsigned short)(py >> 16);
        T2lo[sa] = (unsigned short)(py & 0xFFFFu);
      }
    }
  }
  __syncthreads();
  // ---- phase 2: GEMM, K = [h(64) | T1h(64) | T2h(64) | x-leftover(32)] ----
  int w = tid >> 6, lane = tid & 63, grp = lane >> 4, l15 = lane & 15;
  int row0 = nd0*BB + w*32 + l15, row1 = row0 + 16;
  ffrag acc[2][8];
  #pragma unroll
  for (int m = 0; m < 2; ++m)
    #pragma unroll
    for (int nf = 0; nf < 8; ++nf) acc[m][nf] = (ffrag){0.f, 0.f, 0.f, 0.f};

  #pragma unroll
  for (int ks = 0; ks < 7; ++ks) {
    int ko = (ks & 1)*32 + grp*8;
    bfrag ah0, al0, ah1, al1;
    if (ks < 4) {
      const unsigned* p0 = (ks < 2) ? hP : T1P;
      int st = (ks < 2) ? UU : STR;
      const unsigned* a0 = p0 + (size_t)row0*st + ko;
      const unsigned* a1 = p0 + (size_t)row1*st + ko;
      uint4 q00 = *(const uint4*)a0, q01 = *(const uint4*)(a0 + 4);
      uint4 q10 = *(const uint4*)a1, q11 = *(const uint4*)(a1 + 4);
      unsigned ua0[8] = {q00.x,q00.y,q00.z,q00.w,q01.x,q01.y,q01.z,q01.w};
      unsigned ua1[8] = {q10.x,q10.y,q10.z,q10.w,q11.x,q11.y,q11.z,q11.w};
      #pragma unroll
      for (int jj = 0; jj < 8; ++jj) {
        ah0[jj] = (short)(ua0[jj] >> 16); al0[jj] = (short)(ua0[jj] & 0xFFFFu);
        ah1[jj] = (short)(ua1[jj] >> 16); al1[jj] = (short)(ua1[jj] & 0xFFFFu);
      }
    } else if (ks < 6) {
      int sa0 = (w*32 + l15)*72 + ko;
      int sa1 = (w*32 + l15 + 16)*72 + ko;
      ah0 = *(const bfrag*)(T2hi + sa0); al0 = *(const bfrag*)(T2lo + sa0);
      ah1 = *(const bfrag*)(T2hi + sa1); al1 = *(const bfrag*)(T2lo + sa1);
    } else {
      unsigned ua0[8] = {0,0,0,0,0,0,0,0}, ua1[8] = {0,0,0,0,0,0,0,0};
      if (grp == 0) {
        int sa0 = (w*32 + l15)*72, sa1 = (w*32 + l15 + 16)*72;
        if (CATM == 1) {
          int n0r = row0 >> 5, b0r = row0 & 31, b1r = row1 & 31;
          const unsigned* hx0 = xP + (((size_t)(b0r*LL + t))*NN + n0r)*2;
          const unsigned* hx1 = xP + (((size_t)(b1r*LL + t))*NN + n0r)*2;
          ua0[0] = hx0[0]; ua0[1] = hx0[1];
          ua0[2] = T1P[(size_t)row0*STR + 64]; ua0[3] = T1P[(size_t)row0*STR + 65];
          ua0[4] = ((unsigned)T2hi[sa0+64] << 16) | T2lo[sa0+64];
          ua0[5] = ((unsigned)T2hi[sa0+65] << 16) | T2lo[sa0+65];
          ua1[0] = hx1[0]; ua1[1] = hx1[1];
          ua1[2] = T1P[(size_t)row1*STR + 64]; ua1[3] = T1P[(size_t)row1*STR + 65];
          ua1[4] = ((unsigned)T2hi[sa1+64] << 16) | T2lo[sa1+64];
          ua1[5] = ((unsigned)T2hi[sa1+65] << 16) | T2lo[sa1+65];
        } else {
          ua0[0] = xP[row0];
          ua0[1] = T1P[(size_t)row0*STR + 64];
          ua0[2] = ((unsigned)T2hi[sa0+64] << 16) | T2lo[sa0+64];
          ua1[0] = xP[row1];
          ua1[1] = T1P[(size_t)row1*STR + 64];
          ua1[2] = ((unsigned)T2hi[sa1+64] << 16) | T2lo[sa1+64];
        }
      }
      #pragma unroll
      for (int jj = 0; jj < 8; ++jj) {
        ah0[jj] = (short)(ua0[jj] >> 16); al0[jj] = (short)(ua0[jj] & 0xFFFFu);
        ah1[jj] = (short)(ua1[jj] >> 16); al1[jj] = (short)(ua1[jj] & 0xFFFFu);
      }
    }
    #pragma unroll
    for (int nf = 0; nf < 8; ++nf) {
      const unsigned short* bb = Bpack + (size_t)(nf >> 2)*PACK_HALF
                               + (((size_t)(ks*4 + (nf & 3))*2)*64 + lane)*8;
      bfrag bh = *(const bfrag*)bb;
      bfrag bl = *(const bfrag*)(bb + 512);
      acc[0][nf] = __builtin_amdgcn_mfma_f32_16x16x32_bf16(ah0, bh, acc[0][nf], 0, 0, 0);
      acc[0][nf] = __builtin_amdgcn_mfma_f32_16x16x32_bf16(ah0, bl, acc[0][nf], 0, 0, 0);
      acc[0][nf] = __builtin_amdgcn_mfma_f32_16x16x32_bf16(al0, bh, acc[0][nf], 0, 0, 0);
      acc[1][nf] = __builtin_amdgcn_mfma_f32_16x16x32_bf16(ah1, bh, acc[1][nf], 0, 0, 0);
      acc[1][nf] = __builtin_amdgcn_mfma_f32_16x16x32_bf16(ah1, bl, acc[1][nf], 0, 0, 0);
      acc[1][nf] = __builtin_amdgcn_mfma_f32_16x16x32_bf16(al1, bh, acc[1][nf], 0, 0, 0);
    }
  }
  // ---- epilogue ----
  float bgv[8];
  #pragma unroll
  for (int nf = 0; nf < 8; ++nf) bgv[nf] = bg[nf*16 + l15];
  #pragma unroll
  for (int m = 0; m < 2; ++m)
    #pragma unroll
    for (int reg = 0; reg < 4; ++reg) {
      int row = nd0*BB + w*32 + m*16 + grp*4 + reg;
      #pragma unroll
      for (int nf = 0; nf < 8; ++nf) {
        int col = nf*16 + l15;
        float v = sigm(acc[m][nf][reg] + bgv[nf]);
        if (col < 64) {
          float ho = recsf(hP[(size_t)row*UU + col]);
          zP[(size_t)row*STR + col] = packsf(v * ho);
        } else {
          Ug[(size_t)row*UU + (col - 64)] = v;
        }
      }
    }
  if (l15 == 0) {
    #pragma unroll
    for (int m = 0; m < 2; ++m)
      #pragma unroll
      for (int reg = 0; reg < 4; ++reg) {
        int row = nd0*BB + w*32 + m*16 + grp*4 + reg;
        size_t zb = (size_t)row*STR;
        if (CATM == 1) {
          int n = row >> 5, b = row & 31;
          const unsigned* hx = xP + (((size_t)(b*LL + t))*NN + n)*2;
          zP[zb + 64] = hx[0]; zP[zb + 65] = hx[1];
        } else {
          zP[zb + 64] = xP[row]; zP[zb + 65] = 0u;
        }
        zP[zb + 66] = 0u; zP[zb + 67] = 0u;
      }
  }
}

// ================= fused cand: T2' local + GEMM(224x64) + tanh + GRU (+proj) =================
template<bool DEC>
__global__ __launch_bounds__(256) void k_cand(
    const unsigned* __restrict__ zP, const unsigned* __restrict__ T1P,
    const unsigned short* __restrict__ Bpack, const float* __restrict__ bc,
    const float* __restrict__ Ug, const unsigned* __restrict__ hOld,
    unsigned* __restrict__ hNew,
    const int* __restrict__ rp, const int* __restrict__ cols, const float* __restrict__ vals,
    const float* __restrict__ Wp, const float* __restrict__ bp,
    float* __restrict__ out, unsigned* __restrict__ xioP, int t) {
  __shared__ __align__(16) unsigned short T2hi[4*32*72];
  __shared__ __align__(16) unsigned short T2lo[4*32*72];
  const int CIN_ = DEC ? 1 : 2;
  int tid = threadIdx.x;
  int nd0 = blockIdx.x * 4;
  bool k8 = tid < (SLAB - 2048);
  for (int q = 0; q < 4; ++q) {
    int node = nd0 + q;
    int j0 = rp[node], j1 = rp[node + 1];
    float fa[9];
    #pragma unroll
    for (int k = 0; k < 9; ++k) fa[k] = 0.f;
    int j = j0;
    for (; j + 2 <= j1; j += 2) {
      int n0 = cols[j], n1 = cols[j + 1];
      float s0 = vals[j], s1 = vals[j + 1];
      const unsigned* p0 = T1P + (size_t)n0 * SLAB + tid;
      const unsigned* p1 = T1P + (size_t)n1 * SLAB + tid;
      unsigned u0[9], u1[9];
      #pragma unroll
      for (int k = 0; k < 8; ++k) { u0[k] = p0[k*256]; u1[k] = p1[k*256]; }
      u0[8] = k8 ? p0[2048] : 0u;
      u1[8] = k8 ? p1[2048] : 0u;
      #pragma unroll
      for (int k = 0; k < 9; ++k) {
        fa[k] = fmaf(s0, recsf(u0[k]), fa[k]);
        fa[k] = fmaf(s1, recsf(u1[k]), fa[k]);
      }
    }
    if (j < j1) {
      int n0 = cols[j]; float s0 = vals[j];
      const unsigned* p0 = T1P + (size_t)n0 * SLAB + tid;
      unsigned u0[9];
      #pragma unroll
      for (int k = 0; k < 8; ++k) u0[k] = p0[k*256];
      u0[8] = k8 ? p0[2048] : 0u;
      #pragma unroll
      for (int k = 0; k < 9; ++k) fa[k] = fmaf(s0, recsf(u0[k]), fa[k]);
    }
    #pragma unroll
    for (int k = 0; k < 9; ++k) {
      int idx = tid + k*256;
      if (idx < SLAB) {
        float x0 = recsf(zP[(size_t)node*SLAB + idx]);
        unsigned py = packsf(2.f*fa[k] - x0);
        int b = idx / STR, c = idx - b*STR;
        int sa = (q*32 + b)*72 + c;
        T2hi[sa] = (unsigned short)(py >> 16);
        T2lo[sa] = (unsigned short)(py & 0xFFFFu);
      }
    }
  }
  __syncthreads();
  int w = tid >> 6, lane = tid & 63, grp = lane >> 4, l15 = lane & 15;
  int row0 = nd0*BB + w*32 + l15, row1 = row0 + 16;
  ffrag acc[2][4];
  #pragma unroll
  for (int m = 0; m < 2; ++m)
    #pragma unroll
    for (int nf = 0; nf < 4; ++nf) acc[m][nf] = (ffrag){0.f, 0.f, 0.f, 0.f};

  #pragma unroll
  for (int ks = 0; ks < 7; ++ks) {
    int ko = (ks & 1)*32 + grp*8;
    bfrag ah0, al0, ah1, al1;
    if (ks < 4) {
      const unsigned* p0 = (ks < 2) ? zP : T1P;
      const unsigned* a0 = p0 + (size_t)row0*STR + ko;
      const unsigned* a1 = p0 + (size_t)row1*STR + ko;
      uint4 q00 = *(const uint4*)a0, q01 = *(const uint4*)(a0 + 4);
      uint4 q10 = *(const uint4*)a1, q11 = *(const uint4*)(a1 + 4);
      unsigned ua0[8] = {q00.x,q00.y,q00.z,q00.w,q01.x,q01.y,q01.z,q01.w};
      unsigned ua1[8] = {q10.x,q10.y,q10.z,q10.w,q11.x,q11.y,q11.z,q11.w};
      #pragma unroll
      for (int jj = 0; jj < 8; ++jj) {
        ah0[jj] = (short)(ua0[jj] >> 16); al0[jj] = (short)(ua0[jj] & 0xFFFFu);
        ah1[jj] = (short)(ua1[jj] >> 16); al1[jj] = (short)(ua1[jj] & 0xFFFFu);
      }
    } else if (ks < 6) {
      int sa0 = (w*32 + l15)*72 + ko;
      int sa1 = (w*32 + l15 + 16)*72 + ko;
      ah0 = *(const bfrag*)(T2hi + sa0); al0 = *(const bfrag*)(T2lo + sa0);
      ah1 = *(const bfrag*)(T2hi + sa1); al1 = *(const bfrag*)(T2lo + sa1);
    } else {
      unsigned ua0[8] = {0,0,0,0,0,0,0,0}, ua1[8] = {0,0,0,0,0,0,0,0};
      if (grp == 0) {
        int sa0 = (w*32 + l15)*72, sa1 = (w*32 + l15 + 16)*72;
        if (!DEC) {
          ua0[0] = zP[(size_t)row0*STR + 64];  ua0[1] = zP[(size_t)row0*STR + 65];
          ua0[2] = T1P[(size_t)row0*STR + 64]; ua0[3] = T1P[(size_t)row0*STR + 65];
          ua0[4] = ((unsigned)T2hi[sa0+64] << 16) | T2lo[sa0+64];
          ua0[5] = ((unsigned)T2hi[sa0+65] << 16) | T2lo[sa0+65];
          ua1[0] = zP[(size_t)row1*STR + 64];  ua1[1] = zP[(size_t)row1*STR + 65];
          ua1[2] = T1P[(size_t)row1*STR + 64]; ua1[3] = T1P[(size_t)row1*STR + 65];
          ua1[4] = ((unsigned)T2hi[sa1+64] << 16) | T2lo[sa1+64];
          ua1[5] = ((unsigned)T2hi[sa1+65] << 16) | T2lo[sa1+65];
        } else {
          ua0[0] = zP[(size_t)row0*STR + 64];
          ua0[1] = T1P[(size_t)row0*STR + 64];
          ua0[2] = ((unsigned)T2hi[sa0+64] << 16) | T2lo[sa0+64];
          ua1[0] = zP[(size_t)row1*STR + 64];
          ua1[1] = T1P[(size_t)row1*STR + 64];
          ua1[2] = ((unsigned)T2hi[sa1+64] << 16) | T2lo[sa1+64];
        }
      }
      #pragma unroll
      for (int jj = 0; jj < 8; ++jj) {
        ah0[jj] = (short)(ua0[jj] >> 16); al0[jj] = (short)(ua0[jj] & 0xFFFFu);
        ah1[jj] = (short)(ua1[jj] >> 16); al1[jj] = (short)(ua1[jj] & 0xFFFFu);
      }
    }
    #pragma unroll
    for (int nf = 0; nf < 4; ++nf) {
      const unsigned short* bb = Bpack + (((size_t)(ks*4 + nf)*2)*64 + lane)*8;
      bfrag bh = *(const bfrag*)bb;
      bfrag bl = *(const bfrag*)(bb + 512);
      acc[0][nf] = __builtin_amdgcn_mfma_f32_16x16x32_bf16(ah0, bh, acc[0][nf], 0, 0, 0);
      acc[0][nf] = __builtin_amdgcn_mfma_f32_16x16x32_bf16(ah0, bl, acc[0][nf], 0, 0, 0);
      acc[0][nf] = __builtin_amdgcn_mfma_f32_16x16x32_bf16(al0, bh, acc[0][nf], 0, 0, 0);
      acc[1][nf] = __builtin_amdgcn_mfma_f32_16x16x32_bf16(ah1, bh, acc[1][nf], 0, 0, 0);
      acc[1][nf] = __builtin_amdgcn_mfma_f32_16x16x32_bf16(ah1, bl, acc[1][nf], 0, 0, 0);
      acc[1][nf] = __builtin_amdgcn_mfma_f32_16x16x32_bf16(al1, bh, acc[1][nf], 0, 0, 0);
    }
  }
  float bcv[4], wpv[4];
  #pragma unroll
  for (int nf = 0; nf < 4; ++nf) {
    bcv[nf] = bc[nf*16 + l15];
    wpv[nf] = DEC ? Wp[nf*16 + l15] : 0.f;
  }
  float bp0 = DEC ? bp[0] : 0.f;
  #pragma unroll
  for (int m = 0; m < 2; ++m)
    #pragma unroll
    for (int reg = 0; reg < 4; ++reg) {
      int row = nd0*BB + w*32 + m*16 + grp*4 + reg;
      float p = 0.f;
      #pragma unroll
      for (int nf = 0; nf < 4; ++nf) {
        int col = nf*16 + l15;
        float cf = tanhfast(acc[m][nf][reg] + bcv[nf]);
        float u  = Ug[(size_t)row*UU + col];
        float ho = recsf(hOld[(size_t)row*UU + col]);
        float hv = u * ho + (1.0f - u) * cf;
        hNew[(size_t)row*UU + col] = packsf(hv);
        if (DEC) p = fmaf(hv, wpv[nf], p);
      }
      if (DEC) {
        p += __shfl_xor(p, 1, 64);
        p += __shfl_xor(p, 2, 64);
        p += __shfl_xor(p, 4, 64);
        p += __shfl_xor(p, 8, 64);
        if (l15 == 0) {
          float val = p + bp0;
          int n = row >> 5, b = row & 31;
          out[((size_t)b*HHH + t)*NN + n] = val;
          xioP[row] = packsf(val);
        }
      }
    }
}

extern "C" void kernel_launch(void* const* d_in, const int* in_sizes, int n_in,
                              void* d_out, int out_size, void* d_ws, size_t ws_size,
                              hipStream_t stream) {
  (void)in_sizes; (void)n_in; (void)out_size; (void)ws_size;
  const float* hist = (const float*)d_in[0];
  const float* support = (const float*)d_in[1];
  const float* eWg = (const float*)d_in[2];
  const float* ebg = (const float*)d_in[3];
  const float* eWc = (const float*)d_in[4];
  const float* ebc = (const float*)d_in[5];
  const float* dWg = (const float*)d_in[6];
  const float* dbg = (const float*)d_in[7];
  const float* dWc = (const float*)d_in[8];
  const float* dbc = (const float*)d_in[9];
  const float* Wp  = (const float*)d_in[10];
  const float* bp  = (const float*)d_in[11];
  float* out = (float*)d_out;

  char* base = (char*)d_ws;
  size_t off = 0;
  auto carve = [&](size_t bytes) -> void* {
    void* p = base + off;
    off += (bytes + 255) & ~(size_t)255;
    return p;
  };
  int*   cnt   = (int*)carve(NN * 4);
  int*   rpB   = (int*)carve((NN + 1) * 4);
  int*   colsB = (int*)carve(CSR_CAP * 4);
  float* valsB = (float*)carve(CSR_CAP * 4);
  unsigned short* Pge = (unsigned short*)carve(2 * PACK_HALF * 2);
  unsigned short* Pgd = (unsigned short*)carve(2 * PACK_HALF * 2);
  unsigned short* Pce = (unsigned short*)carve((size_t)PACK_HALF * 2);
  unsigned short* Pcd = (unsigned short*)carve((size_t)PACK_HALF * 2);
  unsigned* histP = (unsigned*)carve((size_t)BB * LL * NN * 2 * 4);
  unsigned* T1P   = (unsigned*)carve((size_t)NN * SLAB * 4);
  unsigned* zP    = (unsigned*)carve((size_t)NN * SLAB * 4);
  float*    UgF   = (float*)carve((size_t)MR * UU * 4);
  unsigned* hPa   = (unsigned*)carve((size_t)MR * UU * 4);
  unsigned* hPb   = (unsigned*)carve((size_t)MR * UU * 4);
  unsigned* xioP  = (unsigned*)carve((size_t)MR * 4);

  hipMemsetAsync(hPa, 0, (size_t)MR * UU * 4, stream);
  hipMemsetAsync(xioP, 0, (size_t)MR * 4, stream);

  k_row_count<<<NN, 256, 0, stream>>>(support, cnt);
  k_scan<<<1, 256, 0, stream>>>(cnt, rpB);
  k_fill<<<NN, 256, 0, stream>>>(support, rpB, colsB, valsB);
  k_pack<<<112, 256, 0, stream>>>(eWg, Pge, 2, 128);
  k_pack<<<56, 256, 0, stream>>>(eWc, Pce, 2, 64);
  k_pack<<<112, 256, 0, stream>>>(dWg, Pgd, 1, 128);
  k_pack<<<56, 256, 0, stream>>>(dWc, Pcd, 1, 64);
  k_packt<<<(BB*LL*NN*2 + 255)/256, 256, 0, stream>>>(hist, histP, BB*LL*NN*2);

  unsigned* hc = hPa; unsigned* hn = hPb;
  for (int t = 0; t < LL; ++t) {
    k_hop<1><<<8192, 256, 0, stream>>>(rpB, colsB, valsB, nullptr, histP, hc, T1P, t);
    k_gate<1><<<NN/4, 256, 0, stream>>>(hc, histP, T1P, Pge, ebg, rpB, colsB, valsB, zP, UgF, t);
    k_hop<0><<<8192, 256, 0, stream>>>(rpB, colsB, valsB, zP, nullptr, nullptr, T1P, t);
    k_cand<false><<<NN/4, 256, 0, stream>>>(zP, T1P, Pce, ebc, UgF, hc, hn,
                                            rpB, colsB, valsB, Wp, bp, out, xioP, t);
    unsigned* tmp = hc; hc = hn; hn = tmp;
  }
  for (int t = 0; t < HHH; ++t) {
    k_hop<2><<<8192, 256, 0, stream>>>(rpB, colsB, valsB, nullptr, xioP, hc, T1P, t);
    k_gate<2><<<NN/4, 256, 0, stream>>>(hc, xioP, T1P, Pgd, dbg, rpB, colsB, valsB, zP, UgF, t);
    k_hop<0><<<8192, 256, 0, stream>>>(rpB, colsB, valsB, zP, nullptr, nullptr, T1P, t);
    k_cand<true><<<NN/4, 256, 0, stream>>>(zP, T1P, Pcd, dbc, UgF, hc, hn,
                                           rpB, colsB, valsB, Wp, bp, out, xioP, t);
    unsigned* tmp = hc; hc = hn; hn = tmp;
  }
}

// Round 5
// 4939.417 us; speedup vs baseline: 1.3503x; 1.3503x over previous
//
#include <hip/hip_runtime.h>
#include <math.h>

#define NN 2048
#define BB 32
#define LL 12
#define HHH 12
#define UU 64
#define STR 68                 // padded row width: [h 64 | x 2 | pad 2]
#define SLAB (BB*STR)          // 2176 u32 per node
#define SEGP (SLAB/4)          // 544
#define MR (NN*BB)             // 65536
#define CSR_CAP 262144
#define PACK_HALF 28672        // 7ks*4nf*2prec*64lane*8j halfwords per 64-col half

typedef short bfrag __attribute__((ext_vector_type(8)));
typedef float ffrag __attribute__((ext_vector_type(4)));

// ---- packed split-bf16: u32 = (bf16(x)<<16) | bf16(x - hi); value = hi_f + lo_f ----
__device__ __forceinline__ unsigned packsf(float x) {
  unsigned u = __float_as_uint(x);
  unsigned hb = (u + 0x7FFFu + ((u >> 16) & 1u)) & 0xFFFF0000u;
  float rem = x - __uint_as_float(hb);
  unsigned lb = __float_as_uint(rem) >> 16;
  return hb | lb;
}
__device__ __forceinline__ float recsf(unsigned u) {
  return __uint_as_float(u & 0xFFFF0000u) + __uint_as_float(u << 16);
}
__device__ __forceinline__ float sigm(float x) { return 1.0f / (1.0f + __expf(-x)); }
__device__ __forceinline__ float tanhfast(float x) {
  float e = __expf(2.0f * x);
  return 1.0f - 2.0f / (e + 1.0f);
}

// ---------------- CSR build (deterministic) ----------------
__global__ __launch_bounds__(256) void k_row_count(const float* __restrict__ S, int* __restrict__ cnt) {
  int m = blockIdx.x;
  const float* row = S + (size_t)m * NN;
  int c = 0;
  for (int i = threadIdx.x; i < NN; i += 256) c += (row[i] != 0.0f);
  __shared__ int sm[4];
  for (int off = 32; off; off >>= 1) c += __shfl_down(c, off, 64);
  if ((threadIdx.x & 63) == 0) sm[threadIdx.x >> 6] = c;
  __syncthreads();
  if (threadIdx.x == 0) cnt[m] = sm[0] + sm[1] + sm[2] + sm[3];
}

__global__ __launch_bounds__(256) void k_scan(const int* __restrict__ cnt, int* __restrict__ rp) {
  __shared__ int tot[256];
  int t = threadIdx.x;
  int base = t * 8;
  int v[8]; int s = 0;
  #pragma unroll
  for (int k = 0; k < 8; ++k) { v[k] = cnt[base + k]; s += v[k]; }
  tot[t] = s;
  __syncthreads();
  for (int off = 1; off < 256; off <<= 1) {
    int add = (t >= off) ? tot[t - off] : 0;
    __syncthreads();
    tot[t] += add;
    __syncthreads();
  }
  int run = (t == 0) ? 0 : tot[t - 1];
  #pragma unroll
  for (int k = 0; k < 8; ++k) { rp[base + k] = run; run += v[k]; }
  if (t == 255) rp[NN] = run;
}

__global__ __launch_bounds__(256) void k_fill(const float* __restrict__ S, const int* __restrict__ rp,
                                              int* __restrict__ cols, float* __restrict__ vals) {
  int m = blockIdx.x;
  const float* row = S + (size_t)m * NN;
  __shared__ int wsum[4];
  __shared__ int chunkbase;
  if (threadIdx.x == 0) chunkbase = rp[m];
  __syncthreads();
  int lane = threadIdx.x & 63, w = threadIdx.x >> 6;
  for (int ch = 0; ch < NN / 256; ++ch) {
    int i = ch * 256 + threadIdx.x;
    float val = row[i];
    bool p = (val != 0.0f);
    unsigned long long mask = __ballot(p);
    int rank = __popcll(mask & ((1ull << lane) - 1ull));
    if (lane == 0) wsum[w] = __popcll(mask);
    __syncthreads();
    int off = 0;
    for (int q = 0; q < w; ++q) off += wsum[q];
    if (p) { int k = chunkbase + off + rank; cols[k] = i; vals[k] = val; }
    __syncthreads();
    if (threadIdx.x == 0) chunkbase += wsum[0] + wsum[1] + wsum[2] + wsum[3];
    __syncthreads();
  }
}

// ---------------- weight pack: fragment-linear bf16 hi/lo ----------------
__global__ __launch_bounds__(256) void k_pack(const float* __restrict__ Wsrc, unsigned short* __restrict__ dst,
                                              int CIN_, int NO) {
  int idx = blockIdx.x * 256 + threadIdx.x;
  int nh_count = NO >> 6;
  int tot = nh_count * 7 * 4 * 64 * 8;
  if (idx >= tot) return;
  int j = idx & 7;
  int r1 = idx >> 3;  int lane = r1 & 63;
  int r2 = r1 >> 6;   int nf = r2 & 3;
  int r3 = r2 >> 2;   int ks = r3 % 7; int nh = r3 / 7;
  int grp = lane >> 4, l15 = lane & 15;
  int col = nh*64 + nf*16 + l15;
  float wv = 0.0f;
  if (ks < 6) {
    int kb = ks >> 1;
    int c = CIN_ + (ks & 1)*32 + grp*8 + j;
    wv = Wsrc[((size_t)c*3 + kb)*NO + col];
  } else {
    int q = grp*8 + j;
    if (q < 3*CIN_) { int kb = q / CIN_, c = q % CIN_; wv = Wsrc[((size_t)c*3 + kb)*NO + col]; }
  }
  unsigned pw = packsf(wv);
  size_t basehi = ((size_t)nh*PACK_HALF) + ((((size_t)ks*4 + nf)*2 + 0)*64 + lane)*8 + j;
  size_t baselo = ((size_t)nh*PACK_HALF) + ((((size_t)ks*4 + nf)*2 + 1)*64 + lane)*8 + j;
  dst[basehi] = (unsigned short)(pw >> 16);
  dst[baselo] = (unsigned short)(pw & 0xFFFFu);
}

__global__ __launch_bounds__(256) void k_packt(const float* __restrict__ src, unsigned* __restrict__ dst, int n) {
  int i = blockIdx.x * 256 + threadIdx.x;
  if (i < n) dst[i] = packsf(src[i]);
}

// ---------------- hop-1: T1 = S . X   (packed in, packed out) ----------------
// SRC: 0 = z-slab, 1 = enc cat [h|hist], 2 = dec cat [h|xio]
// Branchless gather: value(n) = zero ? 0 : bp[n * st]; loads batched 12-deep
// ahead of the recsf+fma pass (VGPR headroom via __launch_bounds__(256,4)).
template<int SRC>
__global__ __launch_bounds__(256, 4) void k_hop(
    const int* __restrict__ rp, const int* __restrict__ cols, const float* __restrict__ vals,
    const unsigned* __restrict__ src, const unsigned* __restrict__ xP,
    const unsigned* __restrict__ hP, unsigned* __restrict__ Y, int t) {
  __shared__ int   scol[64];
  __shared__ float sval[64];
  int orig = blockIdx.x;
  int swz = (orig & 7) * 1024 + (orig >> 3);     // bijective XCD swizzle
  int seg = swz >> 11;
  int node = swz & 2047;
  int j0 = rp[node], j1 = rp[node + 1];
  int tid = threadIdx.x;
  int w0 = seg * SEGP + tid, w1 = w0 + 256, w2 = w0 + 512;
  bool a2 = tid < (SEGP - 512);
  float acc0 = 0.f, acc1 = 0.f, acc2 = 0.f;

  // per-column gather descriptors
  const unsigned *bp0, *bp1, *bp2;
  unsigned st0, st1, st2;
  bool z0 = false, z1 = false, z2 = false;
  if constexpr (SRC == 0) {
    bp0 = src + w0; bp1 = src + w1; bp2 = src + (a2 ? w2 : w0);
    st0 = SLAB; st1 = SLAB; st2 = SLAB;
    z2 = !a2;
  } else {
    auto mk = [&](int wq, const unsigned*& bp, unsigned& st, bool& zz) {
      int b = wq / STR, c = wq - b * STR;
      if (c < 64) { bp = hP + (size_t)b * UU + c; st = BB * UU; }
      else if (SRC == 1 && c < 66) { bp = xP + ((size_t)(b * LL + t)) * NN * 2 + (c - 64); st = 2; }
      else if (SRC == 2 && c == 64) { bp = xP + b; st = BB; }
      else { bp = hP; st = 0; zz = true; }
    };
    mk(w0, bp0, st0, z0);
    mk(w1, bp1, st1, z1);
    if (a2) mk(w2, bp2, st2, z2);
    else { bp2 = hP; st2 = 0; z2 = true; }
  }

  for (int base = j0; base < j1; base += 64) {
    int cnt = min(64, j1 - base);
    if (tid < cnt) { scol[tid] = cols[base + tid]; sval[tid] = vals[base + tid]; }
    __syncthreads();
    int jj = 0;
    for (; jj + 4 <= cnt; jj += 4) {
      unsigned uv[12];
      float sv[4];
      #pragma unroll
      for (int q = 0; q < 4; ++q) {
        unsigned n = (unsigned)scol[jj + q];
        sv[q] = sval[jj + q];
        uv[q*3+0] = bp0[(size_t)(n * st0)];
        uv[q*3+1] = bp1[(size_t)(n * st1)];
        uv[q*3+2] = bp2[(size_t)(n * st2)];
      }
      #pragma unroll
      for (int q = 0; q < 4; ++q) {
        acc0 = fmaf(sv[q], recsf(z0 ? 0u : uv[q*3+0]), acc0);
        acc1 = fmaf(sv[q], recsf(z1 ? 0u : uv[q*3+1]), acc1);
        acc2 = fmaf(sv[q], recsf(z2 ? 0u : uv[q*3+2]), acc2);
      }
    }
    for (; jj < cnt; ++jj) {
      unsigned n = (unsigned)scol[jj]; float s = sval[jj];
      unsigned a = bp0[(size_t)(n * st0)];
      unsigned b = bp1[(size_t)(n * st1)];
      unsigned c = bp2[(size_t)(n * st2)];
      acc0 = fmaf(s, recsf(z0 ? 0u : a), acc0);
      acc1 = fmaf(s, recsf(z1 ? 0u : b), acc1);
      acc2 = fmaf(s, recsf(z2 ? 0u : c), acc2);
    }
    __syncthreads();
  }
  unsigned* yr = Y + (size_t)node * SLAB;
  yr[w0] = packsf(acc0);
  yr[w1] = packsf(acc1);
  if (a2) yr[w2] = packsf(acc2);
}

// ================= fused gate: T2 local + GEMM(224x128) + sigmoid + z/Ug =================
template<int CATM>   // 1 enc, 2 dec
__global__ __launch_bounds__(256) void k_gate(
    const unsigned* __restrict__ hP, const unsigned* __restrict__ xP,
    const unsigned* __restrict__ T1P,
    const unsigned short* __restrict__ Bpack, const float* __restrict__ bg,
    const int* __restrict__ rp, const int* __restrict__ cols, const float* __restrict__ vals,
    unsigned* __restrict__ zP, float* __restrict__ Ug, int t) {
  __shared__ __align__(16) unsigned short T2hi[4*32*72];
  __shared__ __align__(16) unsigned short T2lo[4*32*72];
  int tid = threadIdx.x;
  int nd0 = blockIdx.x * 4;
  // ---- phase 1: T2 = 2 S T1 - cat (local, packed in LDS split planes) ----
  bool k8 = tid < (SLAB - 2048);
  for (int q = 0; q < 4; ++q) {
    int node = nd0 + q;
    int j0 = rp[node], j1 = rp[node + 1];
    float fa[9];
    #pragma unroll
    for (int k = 0; k < 9; ++k) fa[k] = 0.f;
    int j = j0;
    for (; j + 2 <= j1; j += 2) {
      int n0 = cols[j], n1 = cols[j + 1];
      float s0 = vals[j], s1 = vals[j + 1];
      const unsigned* p0 = T1P + (size_t)n0 * SLAB + tid;
      const unsigned* p1 = T1P + (size_t)n1 * SLAB + tid;
      unsigned u0[9], u1[9];
      #pragma unroll
      for (int k = 0; k < 8; ++k) { u0[k] = p0[k*256]; u1[k] = p1[k*256]; }
      u0[8] = k8 ? p0[2048] : 0u;
      u1[8] = k8 ? p1[2048] : 0u;
      #pragma unroll
      for (int k = 0; k < 9; ++k) {
        fa[k] = fmaf(s0, recsf(u0[k]), fa[k]);
        fa[k] = fmaf(s1, recsf(u1[k]), fa[k]);
      }
    }
    if (j < j1) {
      int n0 = cols[j]; float s0 = vals[j];
      const unsigned* p0 = T1P + (size_t)n0 * SLAB + tid;
      unsigned u0[9];
      #pragma unroll
      for (int k = 0; k < 8; ++k) u0[k] = p0[k*256];
      u0[8] = k8 ? p0[2048] : 0u;
      #pragma unroll
      for (int k = 0; k < 9; ++k) fa[k] = fmaf(s0, recsf(u0[k]), fa[k]);
    }
    #pragma unroll
    for (int k = 0; k < 9; ++k) {
      int idx = tid + k*256;
      if (idx < SLAB) {
        int b = idx / STR, c = idx - b*STR;
        int grow = node*BB + b;
        float x0;
        if (c < 64) x0 = recsf(hP[(size_t)grow*UU + c]);
        else if (CATM == 1) x0 = (c < 66) ? recsf(xP[(((size_t)(b*LL + t))*NN + node)*2 + (c - 64)]) : 0.f;
        else x0 = (c == 64) ? recsf(xP[grow]) : 0.f;
        unsigned py = packsf(2.f*fa[k] - x0);
        int sa = (q*32 + b)*72 + c;
        T2hi[sa] = (unsigned short)(py >> 16);
        T2lo[sa] = (unsigned short)(py & 0xFFFFu);
      }
    }
  }
  __syncthreads();
  // ---- phase 2: GEMM, K = [h(64) | T1h(64) | T2h(64) | x-leftover(32)] ----
  int w = tid >> 6, lane = tid & 63, grp = lane >> 4, l15 = lane & 15;
  int row0 = nd0*BB + w*32 + l15, row1 = row0 + 16;
  ffrag acc[2][8];
  #pragma unroll
  for (int m = 0; m < 2; ++m)
    #pragma unroll
    for (int nf = 0; nf < 8; ++nf) acc[m][nf] = (ffrag){0.f, 0.f, 0.f, 0.f};

  #pragma unroll
  for (int ks = 0; ks < 7; ++ks) {
    int ko = (ks & 1)*32 + grp*8;
    bfrag ah0, al0, ah1, al1;
    if (ks < 4) {
      const unsigned* p0 = (ks < 2) ? hP : T1P;
      int st = (ks < 2) ? UU : STR;
      const unsigned* a0 = p0 + (size_t)row0*st + ko;
      const unsigned* a1 = p0 + (size_t)row1*st + ko;
      uint4 q00 = *(const uint4*)a0, q01 = *(const uint4*)(a0 + 4);
      uint4 q10 = *(const uint4*)a1, q11 = *(const uint4*)(a1 + 4);
      unsigned ua0[8] = {q00.x,q00.y,q00.z,q00.w,q01.x,q01.y,q01.z,q01.w};
      unsigned ua1[8] = {q10.x,q10.y,q10.z,q10.w,q11.x,q11.y,q11.z,q11.w};
      #pragma unroll
      for (int jj = 0; jj < 8; ++jj) {
        ah0[jj] = (short)(ua0[jj] >> 16); al0[jj] = (short)(ua0[jj] & 0xFFFFu);
        ah1[jj] = (short)(ua1[jj] >> 16); al1[jj] = (short)(ua1[jj] & 0xFFFFu);
      }
    } else if (ks < 6) {
      int sa0 = (w*32 + l15)*72 + ko;
      int sa1 = (w*32 + l15 + 16)*72 + ko;
      ah0 = *(const bfrag*)(T2hi + sa0); al0 = *(const bfrag*)(T2lo + sa0);
      ah1 = *(const bfrag*)(T2hi + sa1); al1 = *(const bfrag*)(T2lo + sa1);
    } else {
      unsigned ua0[8] = {0,0,0,0,0,0,0,0}, ua1[8] = {0,0,0,0,0,0,0,0};
      if (grp == 0) {
        int sa0 = (w*32 + l15)*72, sa1 = (w*32 + l15 + 16)*72;
        if (CATM == 1) {
          int n0r = row0 >> 5, b0r = row0 & 31, b1r = row1 & 31;
          const unsigned* hx0 = xP + (((size_t)(b0r*LL + t))*NN + n0r)*2;
          const unsigned* hx1 = xP + (((size_t)(b1r*LL + t))*NN + n0r)*2;
          ua0[0] = hx0[0]; ua0[1] = hx0[1];
          ua0[2] = T1P[(size_t)row0*STR + 64]; ua0[3] = T1P[(size_t)row0*STR + 65];
          ua0[4] = ((unsigned)T2hi[sa0+64] << 16) | T2lo[sa0+64];
          ua0[5] = ((unsigned)T2hi[sa0+65] << 16) | T2lo[sa0+65];
          ua1[0] = hx1[0]; ua1[1] = hx1[1];
          ua1[2] = T1P[(size_t)row1*STR + 64]; ua1[3] = T1P[(size_t)row1*STR + 65];
          ua1[4] = ((unsigned)T2hi[sa1+64] << 16) | T2lo[sa1+64];
          ua1[5] = ((unsigned)T2hi[sa1+65] << 16) | T2lo[sa1+65];
        } else {
          ua0[0] = xP[row0];
          ua0[1] = T1P[(size_t)row0*STR + 64];
          ua0[2] = ((unsigned)T2hi[sa0+64] << 16) | T2lo[sa0+64];
          ua1[0] = xP[row1];
          ua1[1] = T1P[(size_t)row1*STR + 64];
          ua1[2] = ((unsigned)T2hi[sa1+64] << 16) | T2lo[sa1+64];
        }
      }
      #pragma unroll
      for (int jj = 0; jj < 8; ++jj) {
        ah0[jj] = (short)(ua0[jj] >> 16); al0[jj] = (short)(ua0[jj] & 0xFFFFu);
        ah1[jj] = (short)(ua1[jj] >> 16); al1[jj] = (short)(ua1[jj] & 0xFFFFu);
      }
    }
    #pragma unroll
    for (int nf = 0; nf < 8; ++nf) {
      const unsigned short* bb = Bpack + (size_t)(nf >> 2)*PACK_HALF
                               + (((size_t)(ks*4 + (nf & 3))*2)*64 + lane)*8;
      bfrag bh = *(const bfrag*)bb;
      bfrag bl = *(const bfrag*)(bb + 512);
      acc[0][nf] = __builtin_amdgcn_mfma_f32_16x16x32_bf16(ah0, bh, acc[0][nf], 0, 0, 0);
      acc[0][nf] = __builtin_amdgcn_mfma_f32_16x16x32_bf16(ah0, bl, acc[0][nf], 0, 0, 0);
      acc[0][nf] = __builtin_amdgcn_mfma_f32_16x16x32_bf16(al0, bh, acc[0][nf], 0, 0, 0);
      acc[1][nf] = __builtin_amdgcn_mfma_f32_16x16x32_bf16(ah1, bh, acc[1][nf], 0, 0, 0);
      acc[1][nf] = __builtin_amdgcn_mfma_f32_16x16x32_bf16(ah1, bl, acc[1][nf], 0, 0, 0);
      acc[1][nf] = __builtin_amdgcn_mfma_f32_16x16x32_bf16(al1, bh, acc[1][nf], 0, 0, 0);
    }
  }
  // ---- epilogue ----
  float bgv[8];
  #pragma unroll
  for (int nf = 0; nf < 8; ++nf) bgv[nf] = bg[nf*16 + l15];
  #pragma unroll
  for (int m = 0; m < 2; ++m)
    #pragma unroll
    for (int reg = 0; reg < 4; ++reg) {
      int row = nd0*BB + w*32 + m*16 + grp*4 + reg;
      #pragma unroll
      for (int nf = 0; nf < 8; ++nf) {
        int col = nf*16 + l15;
        float v = sigm(acc[m][nf][reg] + bgv[nf]);
        if (col < 64) {
          float ho = recsf(hP[(size_t)row*UU + col]);
          zP[(size_t)row*STR + col] = packsf(v * ho);
        } else {
          Ug[(size_t)row*UU + (col - 64)] = v;
        }
      }
    }
  if (l15 == 0) {
    #pragma unroll
    for (int m = 0; m < 2; ++m)
      #pragma unroll
      for (int reg = 0; reg < 4; ++reg) {
        int row = nd0*BB + w*32 + m*16 + grp*4 + reg;
        size_t zb = (size_t)row*STR;
        if (CATM == 1) {
          int n = row >> 5, b = row & 31;
          const unsigned* hx = xP + (((size_t)(b*LL + t))*NN + n)*2;
          zP[zb + 64] = hx[0]; zP[zb + 65] = hx[1];
        } else {
          zP[zb + 64] = xP[row]; zP[zb + 65] = 0u;
        }
        zP[zb + 66] = 0u; zP[zb + 67] = 0u;
      }
  }
}

// ================= fused cand: T2' local + GEMM(224x64) + tanh + GRU (+proj) =================
template<bool DEC>
__global__ __launch_bounds__(256) void k_cand(
    const unsigned* __restrict__ zP, const unsigned* __restrict__ T1P,
    const unsigned short* __restrict__ Bpack, const float* __restrict__ bc,
    const float* __restrict__ Ug, const unsigned* __restrict__ hOld,
    unsigned* __restrict__ hNew,
    const int* __restrict__ rp, const int* __restrict__ cols, const float* __restrict__ vals,
    const float* __restrict__ Wp, const float* __restrict__ bp,
    float* __restrict__ out, unsigned* __restrict__ xioP, int t) {
  __shared__ __align__(16) unsigned short T2hi[4*32*72];
  __shared__ __align__(16) unsigned short T2lo[4*32*72];
  int tid = threadIdx.x;
  int nd0 = blockIdx.x * 4;
  bool k8 = tid < (SLAB - 2048);
  for (int q = 0; q < 4; ++q) {
    int node = nd0 + q;
    int j0 = rp[node], j1 = rp[node + 1];
    float fa[9];
    #pragma unroll
    for (int k = 0; k < 9; ++k) fa[k] = 0.f;
    int j = j0;
    for (; j + 2 <= j1; j += 2) {
      int n0 = cols[j], n1 = cols[j + 1];
      float s0 = vals[j], s1 = vals[j + 1];
      const unsigned* p0 = T1P + (size_t)n0 * SLAB + tid;
      const unsigned* p1 = T1P + (size_t)n1 * SLAB + tid;
      unsigned u0[9], u1[9];
      #pragma unroll
      for (int k = 0; k < 8; ++k) { u0[k] = p0[k*256]; u1[k] = p1[k*256]; }
      u0[8] = k8 ? p0[2048] : 0u;
      u1[8] = k8 ? p1[2048] : 0u;
      #pragma unroll
      for (int k = 0; k < 9; ++k) {
        fa[k] = fmaf(s0, recsf(u0[k]), fa[k]);
        fa[k] = fmaf(s1, recsf(u1[k]), fa[k]);
      }
    }
    if (j < j1) {
      int n0 = cols[j]; float s0 = vals[j];
      const unsigned* p0 = T1P + (size_t)n0 * SLAB + tid;
      unsigned u0[9];
      #pragma unroll
      for (int k = 0; k < 8; ++k) u0[k] = p0[k*256];
      u0[8] = k8 ? p0[2048] : 0u;
      #pragma unroll
      for (int k = 0; k < 9; ++k) fa[k] = fmaf(s0, recsf(u0[k]), fa[k]);
    }
    #pragma unroll
    for (int k = 0; k < 9; ++k) {
      int idx = tid + k*256;
      if (idx < SLAB) {
        float x0 = recsf(zP[(size_t)node*SLAB + idx]);
        unsigned py = packsf(2.f*fa[k] - x0);
        int b = idx / STR, c = idx - b*STR;
        int sa = (q*32 + b)*72 + c;
        T2hi[sa] = (unsigned short)(py >> 16);
        T2lo[sa] = (unsigned short)(py & 0xFFFFu);
      }
    }
  }
  __syncthreads();
  int w = tid >> 6, lane = tid & 63, grp = lane >> 4, l15 = lane & 15;
  int row0 = nd0*BB + w*32 + l15, row1 = row0 + 16;
  ffrag acc[2][4];
  #pragma unroll
  for (int m = 0; m < 2; ++m)
    #pragma unroll
    for (int nf = 0; nf < 4; ++nf) acc[m][nf] = (ffrag){0.f, 0.f, 0.f, 0.f};

  #pragma unroll
  for (int ks = 0; ks < 7; ++ks) {
    int ko = (ks & 1)*32 + grp*8;
    bfrag ah0, al0, ah1, al1;
    if (ks < 4) {
      const unsigned* p0 = (ks < 2) ? zP : T1P;
      const unsigned* a0 = p0 + (size_t)row0*STR + ko;
      const unsigned* a1 = p0 + (size_t)row1*STR + ko;
      uint4 q00 = *(const uint4*)a0, q01 = *(const uint4*)(a0 + 4);
      uint4 q10 = *(const uint4*)a1, q11 = *(const uint4*)(a1 + 4);
      unsigned ua0[8] = {q00.x,q00.y,q00.z,q00.w,q01.x,q01.y,q01.z,q01.w};
      unsigned ua1[8] = {q10.x,q10.y,q10.z,q10.w,q11.x,q11.y,q11.z,q11.w};
      #pragma unroll
      for (int jj = 0; jj < 8; ++jj) {
        ah0[jj] = (short)(ua0[jj] >> 16); al0[jj] = (short)(ua0[jj] & 0xFFFFu);
        ah1[jj] = (short)(ua1[jj] >> 16); al1[jj] = (short)(ua1[jj] & 0xFFFFu);
      }
    } else if (ks < 6) {
      int sa0 = (w*32 + l15)*72 + ko;
      int sa1 = (w*32 + l15 + 16)*72 + ko;
      ah0 = *(const bfrag*)(T2hi + sa0); al0 = *(const bfrag*)(T2lo + sa0);
      ah1 = *(const bfrag*)(T2hi + sa1); al1 = *(const bfrag*)(T2lo + sa1);
    } else {
      unsigned ua0[8] = {0,0,0,0,0,0,0,0}, ua1[8] = {0,0,0,0,0,0,0,0};
      if (grp == 0) {
        int sa0 = (w*32 + l15)*72, sa1 = (w*32 + l15 + 16)*72;
        if (!DEC) {
          ua0[0] = zP[(size_t)row0*STR + 64];  ua0[1] = zP[(size_t)row0*STR + 65];
          ua0[2] = T1P[(size_t)row0*STR + 64]; ua0[3] = T1P[(size_t)row0*STR + 65];
          ua0[4] = ((unsigned)T2hi[sa0+64] << 16) | T2lo[sa0+64];
          ua0[5] = ((unsigned)T2hi[sa0+65] << 16) | T2lo[sa0+65];
          ua1[0] = zP[(size_t)row1*STR + 64];  ua1[1] = zP[(size_t)row1*STR + 65];
          ua1[2] = T1P[(size_t)row1*STR + 64]; ua1[3] = T1P[(size_t)row1*STR + 65];
          ua1[4] = ((unsigned)T2hi[sa1+64] << 16) | T2lo[sa1+64];
          ua1[5] = ((unsigned)T2hi[sa1+65] << 16) | T2lo[sa1+65];
        } else {
          ua0[0] = zP[(size_t)row0*STR + 64];
          ua0[1] = T1P[(size_t)row0*STR + 64];
          ua0[2] = ((unsigned)T2hi[sa0+64] << 16) | T2lo[sa0+64];
          ua1[0] = zP[(size_t)row1*STR + 64];
          ua1[1] = T1P[(size_t)row1*STR + 64];
          ua1[2] = ((unsigned)T2hi[sa1+64] << 16) | T2lo[sa1+64];
        }
      }
      #pragma unroll
      for (int jj = 0; jj < 8; ++jj) {
        ah0[jj] = (short)(ua0[jj] >> 16); al0[jj] = (short)(ua0[jj] & 0xFFFFu);
        ah1[jj] = (short)(ua1[jj] >> 16); al1[jj] = (short)(ua1[jj] & 0xFFFFu);
      }
    }
    #pragma unroll
    for (int nf = 0; nf < 4; ++nf) {
      const unsigned short* bb = Bpack + (((size_t)(ks*4 + nf)*2)*64 + lane)*8;
      bfrag bh = *(const bfrag*)bb;
      bfrag bl = *(const bfrag*)(bb + 512);
      acc[0][nf] = __builtin_amdgcn_mfma_f32_16x16x32_bf16(ah0, bh, acc[0][nf], 0, 0, 0);
      acc[0][nf] = __builtin_amdgcn_mfma_f32_16x16x32_bf16(ah0, bl, acc[0][nf], 0, 0, 0);
      acc[0][nf] = __builtin_amdgcn_mfma_f32_16x16x32_bf16(al0, bh, acc[0][nf], 0, 0, 0);
      acc[1][nf] = __builtin_amdgcn_mfma_f32_16x16x32_bf16(ah1, bh, acc[1][nf], 0, 0, 0);
      acc[1][nf] = __builtin_amdgcn_mfma_f32_16x16x32_bf16(ah1, bl, acc[1][nf], 0, 0, 0);
      acc[1][nf] = __builtin_amdgcn_mfma_f32_16x16x32_bf16(al1, bh, acc[1][nf], 0, 0, 0);
    }
  }
  float bcv[4], wpv[4];
  #pragma unroll
  for (int nf = 0; nf < 4; ++nf) {
    bcv[nf] = bc[nf*16 + l15];
    wpv[nf] = DEC ? Wp[nf*16 + l15] : 0.f;
  }
  float bp0 = DEC ? bp[0] : 0.f;
  #pragma unroll
  for (int m = 0; m < 2; ++m)
    #pragma unroll
    for (int reg = 0; reg < 4; ++reg) {
      int row = nd0*BB + w*32 + m*16 + grp*4 + reg;
      float p = 0.f;
      #pragma unroll
      for (int nf = 0; nf < 4; ++nf) {
        int col = nf*16 + l15;
        float cf = tanhfast(acc[m][nf][reg] + bcv[nf]);
        float u  = Ug[(size_t)row*UU + col];
        float ho = recsf(hOld[(size_t)row*UU + col]);
        float hv = u * ho + (1.0f - u) * cf;
        hNew[(size_t)row*UU + col] = packsf(hv);
        if (DEC) p = fmaf(hv, wpv[nf], p);
      }
      if (DEC) {
        p += __shfl_xor(p, 1, 64);
        p += __shfl_xor(p, 2, 64);
        p += __shfl_xor(p, 4, 64);
        p += __shfl_xor(p, 8, 64);
        if (l15 == 0) {
          float val = p + bp0;
          int n = row >> 5, b = row & 31;
          out[((size_t)b*HHH + t)*NN + n] = val;
          xioP[row] = packsf(val);
        }
      }
    }
}

extern "C" void kernel_launch(void* const* d_in, const int* in_sizes, int n_in,
                              void* d_out, int out_size, void* d_ws, size_t ws_size,
                              hipStream_t stream) {
  (void)in_sizes; (void)n_in; (void)out_size; (void)ws_size;
  const float* hist = (const float*)d_in[0];
  const float* support = (const float*)d_in[1];
  const float* eWg = (const float*)d_in[2];
  const float* ebg = (const float*)d_in[3];
  const float* eWc = (const float*)d_in[4];
  const float* ebc = (const float*)d_in[5];
  const float* dWg = (const float*)d_in[6];
  const float* dbg = (const float*)d_in[7];
  const float* dWc = (const float*)d_in[8];
  const float* dbc = (const float*)d_in[9];
  const float* Wp  = (const float*)d_in[10];
  const float* bp  = (const float*)d_in[11];
  float* out = (float*)d_out;

  char* base = (char*)d_ws;
  size_t off = 0;
  auto carve = [&](size_t bytes) -> void* {
    void* p = base + off;
    off += (bytes + 255) & ~(size_t)255;
    return p;
  };
  int*   cnt   = (int*)carve(NN * 4);
  int*   rpB   = (int*)carve((NN + 1) * 4);
  int*   colsB = (int*)carve(CSR_CAP * 4);
  float* valsB = (float*)carve(CSR_CAP * 4);
  unsigned short* Pge = (unsigned short*)carve(2 * PACK_HALF * 2);
  unsigned short* Pgd = (unsigned short*)carve(2 * PACK_HALF * 2);
  unsigned short* Pce = (unsigned short*)carve((size_t)PACK_HALF * 2);
  unsigned short* Pcd = (unsigned short*)carve((size_t)PACK_HALF * 2);
  unsigned* histP = (unsigned*)carve((size_t)BB * LL * NN * 2 * 4);
  unsigned* T1P   = (unsigned*)carve((size_t)NN * SLAB * 4);
  unsigned* zP    = (unsigned*)carve((size_t)NN * SLAB * 4);
  float*    UgF   = (float*)carve((size_t)MR * UU * 4);
  unsigned* hPa   = (unsigned*)carve((size_t)MR * UU * 4);
  unsigned* hPb   = (unsigned*)carve((size_t)MR * UU * 4);
  unsigned* xioP  = (unsigned*)carve((size_t)MR * 4);

  hipMemsetAsync(hPa, 0, (size_t)MR * UU * 4, stream);
  hipMemsetAsync(xioP, 0, (size_t)MR * 4, stream);

  k_row_count<<<NN, 256, 0, stream>>>(support, cnt);
  k_scan<<<1, 256, 0, stream>>>(cnt, rpB);
  k_fill<<<NN, 256, 0, stream>>>(support, rpB, colsB, valsB);
  k_pack<<<112, 256, 0, stream>>>(eWg, Pge, 2, 128);
  k_pack<<<56, 256, 0, stream>>>(eWc, Pce, 2, 64);
  k_pack<<<112, 256, 0, stream>>>(dWg, Pgd, 1, 128);
  k_pack<<<56, 256, 0, stream>>>(dWc, Pcd, 1, 64);
  k_packt<<<(BB*LL*NN*2 + 255)/256, 256, 0, stream>>>(hist, histP, BB*LL*NN*2);

  unsigned* hc = hPa; unsigned* hn = hPb;
  for (int t = 0; t < LL; ++t) {
    k_hop<1><<<8192, 256, 0, stream>>>(rpB, colsB, valsB, nullptr, histP, hc, T1P, t);
    k_gate<1><<<NN/4, 256, 0, stream>>>(hc, histP, T1P, Pge, ebg, rpB, colsB, valsB, zP, UgF, t);
    k_hop<0><<<8192, 256, 0, stream>>>(rpB, colsB, valsB, zP, nullptr, nullptr, T1P, t);
    k_cand<false><<<NN/4, 256, 0, stream>>>(zP, T1P, Pce, ebc, UgF, hc, hn,
                                            rpB, colsB, valsB, Wp, bp, out, xioP, t);
    unsigned* tmp = hc; hc = hn; hn = tmp;
  }
  for (int t = 0; t < HHH; ++t) {
    k_hop<2><<<8192, 256, 0, stream>>>(rpB, colsB, valsB, nullptr, xioP, hc, T1P, t);
    k_gate<2><<<NN/4, 256, 0, stream>>>(hc, xioP, T1P, Pgd, dbg, rpB, colsB, valsB, zP, UgF, t);
    k_hop<0><<<8192, 256, 0, stream>>>(rpB, colsB, valsB, zP, nullptr, nullptr, T1P, t);
    k_cand<true><<<NN/4, 256, 0, stream>>>(zP, T1P, Pcd, dbc, UgF, hc, hn,
                                           rpB, colsB, valsB, Wp, bp, out, xioP, t);
    unsigned* tmp = hc; hc = hn; hn = tmp;
  }
}

// Round 6
// 3971.437 us; speedup vs baseline: 1.6794x; 1.2437x over previous
//
#include <hip/hip_runtime.h>
#include <math.h>

#define NN 2048
#define BB 32
#define LL 12
#define HHH 12
#define UU 64
#define STR 68                 // padded row width: [h 64 | x 2 | pad 2]
#define SLAB (BB*STR)          // 2176 u32 per node
#define SEGP (SLAB/4)          // 544
#define MR (NN*BB)             // 65536
#define CSR_CAP 262144
#define PACK_HALF 28672        // 7ks*4nf*2prec*64lane*8j halfwords per 64-col half

typedef short bfrag __attribute__((ext_vector_type(8)));
typedef float ffrag __attribute__((ext_vector_type(4)));

// ---- packed split-bf16: u32 = (bf16(x)<<16) | bf16(x - hi); value = hi_f + lo_f ----
__device__ __forceinline__ unsigned packsf(float x) {
  unsigned u = __float_as_uint(x);
  unsigned hb = (u + 0x7FFFu + ((u >> 16) & 1u)) & 0xFFFF0000u;
  float rem = x - __uint_as_float(hb);
  unsigned lb = __float_as_uint(rem) >> 16;
  return hb | lb;
}
__device__ __forceinline__ float recsf(unsigned u) {
  return __uint_as_float(u & 0xFFFF0000u) + __uint_as_float(u << 16);
}
__device__ __forceinline__ float sigm(float x) { return 1.0f / (1.0f + __expf(-x)); }
__device__ __forceinline__ float tanhfast(float x) {
  float e = __expf(2.0f * x);
  return 1.0f - 2.0f / (e + 1.0f);
}

// ---------------- CSR build (deterministic) ----------------
__global__ __launch_bounds__(256) void k_row_count(const float* __restrict__ S, int* __restrict__ cnt) {
  int m = blockIdx.x;
  const float* row = S + (size_t)m * NN;
  int c = 0;
  for (int i = threadIdx.x; i < NN; i += 256) c += (row[i] != 0.0f);
  __shared__ int sm[4];
  for (int off = 32; off; off >>= 1) c += __shfl_down(c, off, 64);
  if ((threadIdx.x & 63) == 0) sm[threadIdx.x >> 6] = c;
  __syncthreads();
  if (threadIdx.x == 0) cnt[m] = sm[0] + sm[1] + sm[2] + sm[3];
}

__global__ __launch_bounds__(256) void k_scan(const int* __restrict__ cnt, int* __restrict__ rp) {
  __shared__ int tot[256];
  int t = threadIdx.x;
  int base = t * 8;
  int v[8]; int s = 0;
  #pragma unroll
  for (int k = 0; k < 8; ++k) { v[k] = cnt[base + k]; s += v[k]; }
  tot[t] = s;
  __syncthreads();
  for (int off = 1; off < 256; off <<= 1) {
    int add = (t >= off) ? tot[t - off] : 0;
    __syncthreads();
    tot[t] += add;
    __syncthreads();
  }
  int run = (t == 0) ? 0 : tot[t - 1];
  #pragma unroll
  for (int k = 0; k < 8; ++k) { rp[base + k] = run; run += v[k]; }
  if (t == 255) rp[NN] = run;
}

__global__ __launch_bounds__(256) void k_fill(const float* __restrict__ S, const int* __restrict__ rp,
                                              int* __restrict__ cols, float* __restrict__ vals) {
  int m = blockIdx.x;
  const float* row = S + (size_t)m * NN;
  __shared__ int wsum[4];
  __shared__ int chunkbase;
  if (threadIdx.x == 0) chunkbase = rp[m];
  __syncthreads();
  int lane = threadIdx.x & 63, w = threadIdx.x >> 6;
  for (int ch = 0; ch < NN / 256; ++ch) {
    int i = ch * 256 + threadIdx.x;
    float val = row[i];
    bool p = (val != 0.0f);
    unsigned long long mask = __ballot(p);
    int rank = __popcll(mask & ((1ull << lane) - 1ull));
    if (lane == 0) wsum[w] = __popcll(mask);
    __syncthreads();
    int off = 0;
    for (int q = 0; q < w; ++q) off += wsum[q];
    if (p) { int k = chunkbase + off + rank; cols[k] = i; vals[k] = val; }
    __syncthreads();
    if (threadIdx.x == 0) chunkbase += wsum[0] + wsum[1] + wsum[2] + wsum[3];
    __syncthreads();
  }
}

// ---------------- weight pack: fragment-linear bf16 hi/lo ----------------
__global__ __launch_bounds__(256) void k_pack(const float* __restrict__ Wsrc, unsigned short* __restrict__ dst,
                                              int CIN_, int NO) {
  int idx = blockIdx.x * 256 + threadIdx.x;
  int nh_count = NO >> 6;
  int tot = nh_count * 7 * 4 * 64 * 8;
  if (idx >= tot) return;
  int j = idx & 7;
  int r1 = idx >> 3;  int lane = r1 & 63;
  int r2 = r1 >> 6;   int nf = r2 & 3;
  int r3 = r2 >> 2;   int ks = r3 % 7; int nh = r3 / 7;
  int grp = lane >> 4, l15 = lane & 15;
  int col = nh*64 + nf*16 + l15;
  float wv = 0.0f;
  if (ks < 6) {
    int kb = ks >> 1;
    int c = CIN_ + (ks & 1)*32 + grp*8 + j;
    wv = Wsrc[((size_t)c*3 + kb)*NO + col];
  } else {
    int q = grp*8 + j;
    if (q < 3*CIN_) { int kb = q / CIN_, c = q % CIN_; wv = Wsrc[((size_t)c*3 + kb)*NO + col]; }
  }
  unsigned pw = packsf(wv);
  size_t basehi = ((size_t)nh*PACK_HALF) + ((((size_t)ks*4 + nf)*2 + 0)*64 + lane)*8 + j;
  size_t baselo = ((size_t)nh*PACK_HALF) + ((((size_t)ks*4 + nf)*2 + 1)*64 + lane)*8 + j;
  dst[basehi] = (unsigned short)(pw >> 16);
  dst[baselo] = (unsigned short)(pw & 0xFFFFu);
}

__global__ __launch_bounds__(256) void k_packt(const float* __restrict__ src, unsigned* __restrict__ dst, int n) {
  int i = blockIdx.x * 256 + threadIdx.x;
  if (i < n) dst[i] = packsf(src[i]);
}

// ---------------- diffusion hop (column-tiled, XCD-L2-resident) ----------------
// SRC: gather source. 0 = packed slab `src`; 1 = enc cat [h|hist]; 2 = dec cat [h|xio]
// X0M: -1: Y = acc; 0: Y = 2*acc - x0p slab; 1/2: Y = 2*acc - cat (enc/dec)
template<int SRC, int X0M>
__global__ __launch_bounds__(256, 4) void k_hop(
    const int* __restrict__ rp, const int* __restrict__ cols, const float* __restrict__ vals,
    const unsigned* __restrict__ src, const unsigned* __restrict__ xP,
    const unsigned* __restrict__ hP, const unsigned* __restrict__ x0p,
    unsigned* __restrict__ Y, int t) {
  __shared__ int   scol[64];
  __shared__ float sval[64];
  int orig = blockIdx.x;
  int swz = (orig & 7) * 1024 + (orig >> 3);     // bijective XCD swizzle
  int seg = swz >> 11;
  int node = swz & 2047;
  int j0 = rp[node], j1 = rp[node + 1];
  int tid = threadIdx.x;
  int w0 = seg * SEGP + tid, w1 = w0 + 256, w2 = w0 + 512;
  bool a2 = tid < (SEGP - 512);
  float acc0 = 0.f, acc1 = 0.f, acc2 = 0.f;

  int b0 = 0, c0 = 0, b1 = 0, c1 = 0, b2 = 0, c2 = 0;
  if constexpr (SRC != 0 || X0M > 0) {
    b0 = w0 / STR; c0 = w0 - b0 * STR;
    b1 = w1 / STR; c1 = w1 - b1 * STR;
    b2 = w2 / STR; c2 = w2 - b2 * STR;
  }

  // per-column gather descriptors
  const unsigned *bp0, *bp1, *bp2;
  unsigned st0, st1, st2;
  bool z0 = false, z1 = false, z2 = false;
  if constexpr (SRC == 0) {
    bp0 = src + w0; bp1 = src + w1; bp2 = src + (a2 ? w2 : w0);
    st0 = SLAB; st1 = SLAB; st2 = SLAB;
    z2 = !a2;
  } else {
    auto mk = [&](int b, int c, const unsigned*& bp, unsigned& st, bool& zz) {
      if (c < 64) { bp = hP + (size_t)b * UU + c; st = BB * UU; }
      else if (SRC == 1 && c < 66) { bp = xP + ((size_t)(b * LL + t)) * NN * 2 + (c - 64); st = 2; }
      else if (SRC == 2 && c == 64) { bp = xP + b; st = BB; }
      else { bp = hP; st = 0; zz = true; }
    };
    mk(b0, c0, bp0, st0, z0);
    mk(b1, c1, bp1, st1, z1);
    if (a2) mk(b2, c2, bp2, st2, z2);
    else { bp2 = hP; st2 = 0; z2 = true; }
  }

  for (int base = j0; base < j1; base += 64) {
    int cnt = min(64, j1 - base);
    if (tid < cnt) { scol[tid] = cols[base + tid]; sval[tid] = vals[base + tid]; }
    __syncthreads();
    int jj = 0;
    for (; jj + 4 <= cnt; jj += 4) {
      unsigned uv[12];
      float sv[4];
      #pragma unroll
      for (int q = 0; q < 4; ++q) {
        unsigned n = (unsigned)scol[jj + q];
        sv[q] = sval[jj + q];
        uv[q*3+0] = bp0[(size_t)(n * st0)];
        uv[q*3+1] = bp1[(size_t)(n * st1)];
        uv[q*3+2] = bp2[(size_t)(n * st2)];
      }
      #pragma unroll
      for (int q = 0; q < 4; ++q) {
        acc0 = fmaf(sv[q], recsf(z0 ? 0u : uv[q*3+0]), acc0);
        acc1 = fmaf(sv[q], recsf(z1 ? 0u : uv[q*3+1]), acc1);
        acc2 = fmaf(sv[q], recsf(z2 ? 0u : uv[q*3+2]), acc2);
      }
    }
    for (; jj < cnt; ++jj) {
      unsigned n = (unsigned)scol[jj]; float s = sval[jj];
      unsigned a = bp0[(size_t)(n * st0)];
      unsigned b = bp1[(size_t)(n * st1)];
      unsigned c = bp2[(size_t)(n * st2)];
      acc0 = fmaf(s, recsf(z0 ? 0u : a), acc0);
      acc1 = fmaf(s, recsf(z1 ? 0u : b), acc1);
      acc2 = fmaf(s, recsf(z2 ? 0u : c), acc2);
    }
    __syncthreads();
  }

  unsigned* yr = Y + (size_t)node * SLAB;
  if constexpr (X0M < 0) {
    yr[w0] = packsf(acc0);
    yr[w1] = packsf(acc1);
    if (a2) yr[w2] = packsf(acc2);
  } else {
    auto X0V = [&](int wq, int b, int c) -> float {
      if constexpr (X0M == 0) {
        return recsf(x0p[(size_t)node * SLAB + wq]);
      } else if constexpr (X0M == 1) {
        if (c < 64) return recsf(hP[((size_t)node * BB + b) * UU + c]);
        if (c < 66) return recsf(xP[(((size_t)(b * LL + t)) * NN + node) * 2 + (c - 64)]);
        return 0.f;
      } else {
        if (c < 64) return recsf(hP[((size_t)node * BB + b) * UU + c]);
        if (c == 64) return recsf(xP[(size_t)node * BB + b]);
        return 0.f;
      }
    };
    yr[w0] = packsf(2.f * acc0 - X0V(w0, b0, c0));
    yr[w1] = packsf(2.f * acc1 - X0V(w1, b1, c1));
    if (a2) yr[w2] = packsf(2.f * acc2 - X0V(w2, b2, c2));
  }
}

// ================= gate GEMM (pure, streaming): ru = sigmoid(A@Wg+bg) -> z, Ug =================
// 64 rows/block, 128 cols, K = [h 64 | T1h 64 | T2h 64 | x-leftover 32]
template<int CATM>   // 1 enc, 2 dec
__global__ __launch_bounds__(256, 4) void k_gate(
    const unsigned* __restrict__ hP, const unsigned* __restrict__ xP,
    const unsigned* __restrict__ T1P, const unsigned* __restrict__ T2P,
    const unsigned short* __restrict__ Bpack, const float* __restrict__ bg,
    unsigned* __restrict__ zP, float* __restrict__ Ug, int t) {
  int tid = threadIdx.x;
  int r0 = blockIdx.x * 64;
  int w = tid >> 6, lane = tid & 63, grp = lane >> 4, l15 = lane & 15;
  int row0 = r0 + w*16 + l15;
  ffrag acc[8];
  #pragma unroll
  for (int nf = 0; nf < 8; ++nf) acc[nf] = (ffrag){0.f, 0.f, 0.f, 0.f};

  #pragma unroll
  for (int ks = 0; ks < 7; ++ks) {
    int ko = (ks & 1)*32 + grp*8;
    bfrag ah0, al0;
    if (ks < 6) {
      const unsigned* p0; int st;
      if (ks < 2)      { p0 = hP;  st = UU; }
      else if (ks < 4) { p0 = T1P; st = STR; }
      else             { p0 = T2P; st = STR; }
      const unsigned* a0 = p0 + (size_t)row0*st + ko;
      uint4 q00 = *(const uint4*)a0, q01 = *(const uint4*)(a0 + 4);
      unsigned ua0[8] = {q00.x,q00.y,q00.z,q00.w,q01.x,q01.y,q01.z,q01.w};
      #pragma unroll
      for (int jj = 0; jj < 8; ++jj) {
        ah0[jj] = (short)(ua0[jj] >> 16); al0[jj] = (short)(ua0[jj] & 0xFFFFu);
      }
    } else {
      unsigned ua0[8] = {0,0,0,0,0,0,0,0};
      if (grp == 0) {
        if (CATM == 1) {
          int n0r = row0 >> 5, b0r = row0 & 31;
          const unsigned* hx0 = xP + (((size_t)(b0r*LL + t))*NN + n0r)*2;
          ua0[0] = hx0[0]; ua0[1] = hx0[1];
          ua0[2] = T1P[(size_t)row0*STR + 64]; ua0[3] = T1P[(size_t)row0*STR + 65];
          ua0[4] = T2P[(size_t)row0*STR + 64]; ua0[5] = T2P[(size_t)row0*STR + 65];
        } else {
          ua0[0] = xP[row0];
          ua0[1] = T1P[(size_t)row0*STR + 64];
          ua0[2] = T2P[(size_t)row0*STR + 64];
        }
      }
      #pragma unroll
      for (int jj = 0; jj < 8; ++jj) {
        ah0[jj] = (short)(ua0[jj] >> 16); al0[jj] = (short)(ua0[jj] & 0xFFFFu);
      }
    }
    #pragma unroll
    for (int nf = 0; nf < 8; ++nf) {
      const unsigned short* bb = Bpack + (size_t)(nf >> 2)*PACK_HALF
                               + (((size_t)(ks*4 + (nf & 3))*2)*64 + lane)*8;
      bfrag bh = *(const bfrag*)bb;
      bfrag bl = *(const bfrag*)(bb + 512);
      acc[nf] = __builtin_amdgcn_mfma_f32_16x16x32_bf16(ah0, bh, acc[nf], 0, 0, 0);
      acc[nf] = __builtin_amdgcn_mfma_f32_16x16x32_bf16(ah0, bl, acc[nf], 0, 0, 0);
      acc[nf] = __builtin_amdgcn_mfma_f32_16x16x32_bf16(al0, bh, acc[nf], 0, 0, 0);
    }
  }
  // ---- epilogue ----
  float bgv[8];
  #pragma unroll
  for (int nf = 0; nf < 8; ++nf) bgv[nf] = bg[nf*16 + l15];
  #pragma unroll
  for (int reg = 0; reg < 4; ++reg) {
    int row = r0 + w*16 + grp*4 + reg;
    #pragma unroll
    for (int nf = 0; nf < 8; ++nf) {
      int col = nf*16 + l15;
      float v = sigm(acc[nf][reg] + bgv[nf]);
      if (col < 64) {
        float ho = recsf(hP[(size_t)row*UU + col]);
        zP[(size_t)row*STR + col] = packsf(v * ho);
      } else {
        Ug[(size_t)row*UU + (col - 64)] = v;
      }
    }
  }
  if (l15 == 0) {
    #pragma unroll
    for (int reg = 0; reg < 4; ++reg) {
      int row = r0 + w*16 + grp*4 + reg;
      size_t zb = (size_t)row*STR;
      if (CATM == 1) {
        int n = row >> 5, b = row & 31;
        const unsigned* hx = xP + (((size_t)(b*LL + t))*NN + n)*2;
        zP[zb + 64] = hx[0]; zP[zb + 65] = hx[1];
      } else {
        zP[zb + 64] = xP[row]; zP[zb + 65] = 0u;
      }
      zP[zb + 66] = 0u; zP[zb + 67] = 0u;
    }
  }
}

// ================= cand GEMM (pure): c = tanh(A@Wc+bc); h = u*h+(1-u)*c (+proj) =================
// 64 rows/block, 64 cols
template<bool DEC>
__global__ __launch_bounds__(256, 4) void k_cand(
    const unsigned* __restrict__ zP, const unsigned* __restrict__ T1P,
    const unsigned* __restrict__ T2P,
    const unsigned short* __restrict__ Bpack, const float* __restrict__ bc,
    const float* __restrict__ Ug, const unsigned* __restrict__ hOld,
    unsigned* __restrict__ hNew,
    const float* __restrict__ Wp, const float* __restrict__ bp,
    float* __restrict__ out, unsigned* __restrict__ xioP, int t) {
  int tid = threadIdx.x;
  int r0 = blockIdx.x * 64;
  int w = tid >> 6, lane = tid & 63, grp = lane >> 4, l15 = lane & 15;
  int row0 = r0 + w*16 + l15;
  ffrag acc[4];
  #pragma unroll
  for (int nf = 0; nf < 4; ++nf) acc[nf] = (ffrag){0.f, 0.f, 0.f, 0.f};

  #pragma unroll
  for (int ks = 0; ks < 7; ++ks) {
    int ko = (ks & 1)*32 + grp*8;
    bfrag ah0, al0;
    if (ks < 6) {
      const unsigned* p0;
      if (ks < 2)      p0 = zP;
      else if (ks < 4) p0 = T1P;
      else             p0 = T2P;
      const unsigned* a0 = p0 + (size_t)row0*STR + ko;
      uint4 q00 = *(const uint4*)a0, q01 = *(const uint4*)(a0 + 4);
      unsigned ua0[8] = {q00.x,q00.y,q00.z,q00.w,q01.x,q01.y,q01.z,q01.w};
      #pragma unroll
      for (int jj = 0; jj < 8; ++jj) {
        ah0[jj] = (short)(ua0[jj] >> 16); al0[jj] = (short)(ua0[jj] & 0xFFFFu);
      }
    } else {
      unsigned ua0[8] = {0,0,0,0,0,0,0,0};
      if (grp == 0) {
        if (!DEC) {
          ua0[0] = zP[(size_t)row0*STR + 64];  ua0[1] = zP[(size_t)row0*STR + 65];
          ua0[2] = T1P[(size_t)row0*STR + 64]; ua0[3] = T1P[(size_t)row0*STR + 65];
          ua0[4] = T2P[(size_t)row0*STR + 64]; ua0[5] = T2P[(size_t)row0*STR + 65];
        } else {
          ua0[0] = zP[(size_t)row0*STR + 64];
          ua0[1] = T1P[(size_t)row0*STR + 64];
          ua0[2] = T2P[(size_t)row0*STR + 64];
        }
      }
      #pragma unroll
      for (int jj = 0; jj < 8; ++jj) {
        ah0[jj] = (short)(ua0[jj] >> 16); al0[jj] = (short)(ua0[jj] & 0xFFFFu);
      }
    }
    #pragma unroll
    for (int nf = 0; nf < 4; ++nf) {
      const unsigned short* bb = Bpack + (((size_t)(ks*4 + nf)*2)*64 + lane)*8;
      bfrag bh = *(const bfrag*)bb;
      bfrag bl = *(const bfrag*)(bb + 512);
      acc[nf] = __builtin_amdgcn_mfma_f32_16x16x32_bf16(ah0, bh, acc[nf], 0, 0, 0);
      acc[nf] = __builtin_amdgcn_mfma_f32_16x16x32_bf16(ah0, bl, acc[nf], 0, 0, 0);
      acc[nf] = __builtin_amdgcn_mfma_f32_16x16x32_bf16(al0, bh, acc[nf], 0, 0, 0);
    }
  }
  float bcv[4], wpv[4];
  #pragma unroll
  for (int nf = 0; nf < 4; ++nf) {
    bcv[nf] = bc[nf*16 + l15];
    wpv[nf] = DEC ? Wp[nf*16 + l15] : 0.f;
  }
  float bp0 = DEC ? bp[0] : 0.f;
  #pragma unroll
  for (int reg = 0; reg < 4; ++reg) {
    int row = r0 + w*16 + grp*4 + reg;
    float p = 0.f;
    #pragma unroll
    for (int nf = 0; nf < 4; ++nf) {
      int col = nf*16 + l15;
      float cf = tanhfast(acc[nf][reg] + bcv[nf]);
      float u  = Ug[(size_t)row*UU + col];
      float ho = recsf(hOld[(size_t)row*UU + col]);
      float hv = u * ho + (1.0f - u) * cf;
      hNew[(size_t)row*UU + col] = packsf(hv);
      if (DEC) p = fmaf(hv, wpv[nf], p);
    }
    if (DEC) {
      p += __shfl_xor(p, 1, 64);
      p += __shfl_xor(p, 2, 64);
      p += __shfl_xor(p, 4, 64);
      p += __shfl_xor(p, 8, 64);
      if (l15 == 0) {
        float val = p + bp0;
        int n = row >> 5, b = row & 31;
        out[((size_t)b*HHH + t)*NN + n] = val;
        xioP[row] = packsf(val);
      }
    }
  }
}

extern "C" void kernel_launch(void* const* d_in, const int* in_sizes, int n_in,
                              void* d_out, int out_size, void* d_ws, size_t ws_size,
                              hipStream_t stream) {
  (void)in_sizes; (void)n_in; (void)out_size; (void)ws_size;
  const float* hist = (const float*)d_in[0];
  const float* support = (const float*)d_in[1];
  const float* eWg = (const float*)d_in[2];
  const float* ebg = (const float*)d_in[3];
  const float* eWc = (const float*)d_in[4];
  const float* ebc = (const float*)d_in[5];
  const float* dWg = (const float*)d_in[6];
  const float* dbg = (const float*)d_in[7];
  const float* dWc = (const float*)d_in[8];
  const float* dbc = (const float*)d_in[9];
  const float* Wp  = (const float*)d_in[10];
  const float* bp  = (const float*)d_in[11];
  float* out = (float*)d_out;

  char* base = (char*)d_ws;
  size_t off = 0;
  auto carve = [&](size_t bytes) -> void* {
    void* p = base + off;
    off += (bytes + 255) & ~(size_t)255;
    return p;
  };
  int*   cnt   = (int*)carve(NN * 4);
  int*   rpB   = (int*)carve((NN + 1) * 4);
  int*   colsB = (int*)carve(CSR_CAP * 4);
  float* valsB = (float*)carve(CSR_CAP * 4);
  unsigned short* Pge = (unsigned short*)carve(2 * PACK_HALF * 2);
  unsigned short* Pgd = (unsigned short*)carve(2 * PACK_HALF * 2);
  unsigned short* Pce = (unsigned short*)carve((size_t)PACK_HALF * 2);
  unsigned short* Pcd = (unsigned short*)carve((size_t)PACK_HALF * 2);
  unsigned* histP = (unsigned*)carve((size_t)BB * LL * NN * 2 * 4);
  unsigned* T1P   = (unsigned*)carve((size_t)NN * SLAB * 4);
  unsigned* T2P   = (unsigned*)carve((size_t)NN * SLAB * 4);
  unsigned* zP    = (unsigned*)carve((size_t)NN * SLAB * 4);
  float*    UgF   = (float*)carve((size_t)MR * UU * 4);
  unsigned* hPa   = (unsigned*)carve((size_t)MR * UU * 4);
  unsigned* hPb   = (unsigned*)carve((size_t)MR * UU * 4);
  unsigned* xioP  = (unsigned*)carve((size_t)MR * 4);

  hipMemsetAsync(hPa, 0, (size_t)MR * UU * 4, stream);
  hipMemsetAsync(xioP, 0, (size_t)MR * 4, stream);

  k_row_count<<<NN, 256, 0, stream>>>(support, cnt);
  k_scan<<<1, 256, 0, stream>>>(cnt, rpB);
  k_fill<<<NN, 256, 0, stream>>>(support, rpB, colsB, valsB);
  k_pack<<<112, 256, 0, stream>>>(eWg, Pge, 2, 128);
  k_pack<<<56, 256, 0, stream>>>(eWc, Pce, 2, 64);
  k_pack<<<112, 256, 0, stream>>>(dWg, Pgd, 1, 128);
  k_pack<<<56, 256, 0, stream>>>(dWc, Pcd, 1, 64);
  k_packt<<<(BB*LL*NN*2 + 255)/256, 256, 0, stream>>>(hist, histP, BB*LL*NN*2);

  unsigned* hc = hPa; unsigned* hn = hPb;
  for (int t = 0; t < LL; ++t) {
    k_hop<1,-1><<<8192, 256, 0, stream>>>(rpB, colsB, valsB, nullptr, histP, hc, nullptr, T1P, t);
    k_hop<0, 1><<<8192, 256, 0, stream>>>(rpB, colsB, valsB, T1P, histP, hc, nullptr, T2P, t);
    k_gate<1><<<MR/64, 256, 0, stream>>>(hc, histP, T1P, T2P, Pge, ebg, zP, UgF, t);
    k_hop<0,-1><<<8192, 256, 0, stream>>>(rpB, colsB, valsB, zP, nullptr, nullptr, nullptr, T1P, t);
    k_hop<0, 0><<<8192, 256, 0, stream>>>(rpB, colsB, valsB, T1P, nullptr, nullptr, zP, T2P, t);
    k_cand<false><<<MR/64, 256, 0, stream>>>(zP, T1P, T2P, Pce, ebc, UgF, hc, hn,
                                             Wp, bp, out, xioP, t);
    unsigned* tmp = hc; hc = hn; hn = tmp;
  }
  for (int t = 0; t < HHH; ++t) {
    k_hop<2,-1><<<8192, 256, 0, stream>>>(rpB, colsB, valsB, nullptr, xioP, hc, nullptr, T1P, t);
    k_hop<0, 2><<<8192, 256, 0, stream>>>(rpB, colsB, valsB, T1P, xioP, hc, nullptr, T2P, t);
    k_gate<2><<<MR/64, 256, 0, stream>>>(hc, xioP, T1P, T2P, Pgd, dbg, zP, UgF, t);
    k_hop<0,-1><<<8192, 256, 0, stream>>>(rpB, colsB, valsB, zP, nullptr, nullptr, nullptr, T1P, t);
    k_hop<0, 0><<<8192, 256, 0, stream>>>(rpB, colsB, valsB, T1P, nullptr, nullptr, zP, T2P, t);
    k_cand<true><<<MR/64, 256, 0, stream>>>(zP, T1P, T2P, Pcd, dbc, UgF, hc, hn,
                                            Wp, bp, out, xioP, t);
    unsigned* tmp = hc; hc = hn; hn = tmp;
  }
}